// Round 4
// baseline (775.693 us; speedup 1.0000x reference)
//
#include <hip/hip_runtime.h>
#include <math.h>

// ---------------------------------------------------------------------------
// RoadNetworkEncoder: 2x GATv2 (road) + 2x GCN (zone), f32, H=128.
// CSR pull-aggregation (no feature atomics), online softmax.
// Round 4: cache-only GEMM (no LDS). Round-3 LDS GEMM was LDS-pipe bound
// (8 ds_read_b128 vs 64 FMA per k0, 2 blocks/CU -> VALUBusy 41%). All LDS
// reads were 16-lane broadcasts -> serve from L1 instead; occupancy unbound.
// ---------------------------------------------------------------------------

__global__ __launch_bounds__(256) void feat_kernel(
    const float* __restrict__ id_emb, const float* __restrict__ lenW, const float* __restrict__ lenb,
    const float* __restrict__ type_emb, const float* __restrict__ lonW, const float* __restrict__ lonb,
    const float* __restrict__ latW, const float* __restrict__ latb,
    const float* __restrict__ alen, const int* __restrict__ atype,
    const float* __restrict__ alon, const float* __restrict__ alat,
    float* __restrict__ x, int N) {
  int idx = blockIdx.x * 256 + threadIdx.x;
  if (idx >= N * 128) return;
  int node = idx >> 7, j = idx & 127;
  float v;
  if (j < 64) v = id_emb[(node << 6) + j];
  else if (j < 80) v = alen[node] * lenW[j - 64] + lenb[j - 64];
  else if (j < 96) v = type_emb[atype[node] * 16 + (j - 80)];
  else if (j < 112) v = alon[node] * lonW[j - 96] + lonb[j - 96];
  else v = alat[node] * latW[j - 112] + latb[j - 112];
  x[idx] = v;
}

// ------------------------- CSR build -------------------------

__global__ __launch_bounds__(256) void hist_kernel(const int* __restrict__ dst, int* __restrict__ hist, int E) {
  int e = blockIdx.x * 256 + threadIdx.x;
  if (e < E) atomicAdd(hist + dst[e], 1);
}

// exclusive scan, 1024 elems/block (256 thr x 4)
__global__ __launch_bounds__(256) void scan_local(const int* __restrict__ in, int* __restrict__ out,
                                                  int* __restrict__ bsum, int n) {
  __shared__ int lds[256];
  int t = threadIdx.x;
  int base = blockIdx.x * 1024 + t * 4;
  int v0 = base + 0 < n ? in[base + 0] : 0;
  int v1 = base + 1 < n ? in[base + 1] : 0;
  int v2 = base + 2 < n ? in[base + 2] : 0;
  int v3 = base + 3 < n ? in[base + 3] : 0;
  int s = v0 + v1 + v2 + v3;
  lds[t] = s;
  __syncthreads();
  for (int off = 1; off < 256; off <<= 1) {
    int x = (t >= off) ? lds[t - off] : 0;
    __syncthreads();
    if (t >= off) lds[t] += x;
    __syncthreads();
  }
  int excl = lds[t] - s;
  if (t == 255) bsum[blockIdx.x] = lds[255];
  if (base + 0 < n) out[base + 0] = excl;
  if (base + 1 < n) out[base + 1] = excl + v0;
  if (base + 2 < n) out[base + 2] = excl + v0 + v1;
  if (base + 3 < n) out[base + 3] = excl + v0 + v1 + v2;
}

__global__ __launch_bounds__(256) void scan_bsum(int* __restrict__ bsum, int nb) {
  __shared__ int lds[256];
  int t = threadIdx.x;
  int v = (t < nb) ? bsum[t] : 0;
  lds[t] = v;
  __syncthreads();
  for (int off = 1; off < 256; off <<= 1) {
    int x = (t >= off) ? lds[t - off] : 0;
    __syncthreads();
    if (t >= off) lds[t] += x;
    __syncthreads();
  }
  if (t < nb) bsum[t] = lds[t] - v;
}

__global__ __launch_bounds__(256) void scan_add(int* __restrict__ out, const int* __restrict__ bsum, int n) {
  int i = blockIdx.x * 256 + threadIdx.x;
  if (i < n) out[i] += bsum[i >> 10];
}

__global__ __launch_bounds__(256) void scatter_road(const int* __restrict__ src, const int* __restrict__ dst,
                                                    const int* __restrict__ rowstart, int* __restrict__ cursor,
                                                    int* __restrict__ csr_src, int* __restrict__ csr_eid, int E) {
  int e = blockIdx.x * 256 + threadIdx.x;
  if (e >= E) return;
  int d = dst[e];
  int idx = rowstart[d] + atomicAdd(cursor + d, 1);
  csr_src[idx] = src[e];
  csr_eid[idx] = e;
}

__global__ __launch_bounds__(256) void scatter_zone(const int* __restrict__ src, const int* __restrict__ dst,
                                                    const float* __restrict__ w,
                                                    const int* __restrict__ rowstart, int* __restrict__ cursor,
                                                    int* __restrict__ csr_src, float* __restrict__ csr_w, int E) {
  int e = blockIdx.x * 256 + threadIdx.x;
  if (e >= E) return;
  int d = dst[e];
  int idx = rowstart[d] + atomicAdd(cursor + d, 1);
  csr_src[idx] = src[e];
  csr_w[idx] = w[e];
}

__global__ __launch_bounds__(256) void mean_ea_kernel(const int* __restrict__ rowstart, const int* __restrict__ hist,
                                                      const int* __restrict__ csr_eid, const float* __restrict__ ia,
                                                      float* __restrict__ mea, int N) {
  int d = blockIdx.x * 256 + threadIdx.x;
  if (d >= N) return;
  int st = rowstart[d], deg = hist[d];
  float a = 0.f, b = 0.f;
  for (int i = 0; i < deg; ++i) {
    int e = csr_eid[st + i];
    a += ia[2 * e];
    b += ia[2 * e + 1];
  }
  float c = deg > 0 ? 1.f / (float)deg : 0.f;
  mea[2 * d] = a * c;
  mea[2 * d + 1] = b * c;
}

// ------------------------- GEMM 128x128 weights -------------------------
// Y[N,128] = X[N,128] @ W[128,128] (+bias) (relu). Block: 64 rows x 64 cols.
// No LDS: X row addrs are 16-lane-shared, W row reads are contiguous 256 B
// per wave -> L1 broadcasts. Block touches 32 KB X + 32 KB W.
__global__ __launch_bounds__(256) void gemm128(const float* __restrict__ X, const float* __restrict__ W,
                                               const float* __restrict__ bias, float* __restrict__ Y,
                                               int N, int relu) {
  int t = threadIdx.x;
  int c = t & 15, g = t >> 4;
  int row0 = (blockIdx.x >> 1) * 64;
  int col0 = (blockIdx.x & 1) * 64;
  int r = row0 + g * 4;
  const float* x0 = X + (size_t)min(r + 0, N - 1) * 128;
  const float* x1 = X + (size_t)min(r + 1, N - 1) * 128;
  const float* x2 = X + (size_t)min(r + 2, N - 1) * 128;
  const float* x3 = X + (size_t)min(r + 3, N - 1) * 128;
  const float* wp = W + col0 + c * 4;
  float acc[4][4] = {{0.f}};
  // bounded unroll: full unroll spilled in round 2 (VGPR 256, scratch-bound)
#pragma unroll 2
  for (int k0 = 0; k0 < 128; k0 += 4) {
    float4 a0 = *reinterpret_cast<const float4*>(x0 + k0);
    float4 a1 = *reinterpret_cast<const float4*>(x1 + k0);
    float4 a2 = *reinterpret_cast<const float4*>(x2 + k0);
    float4 a3 = *reinterpret_cast<const float4*>(x3 + k0);
    float4 w0 = *reinterpret_cast<const float4*>(wp + (size_t)(k0 + 0) * 128);
    float4 w1 = *reinterpret_cast<const float4*>(wp + (size_t)(k0 + 1) * 128);
    float4 w2 = *reinterpret_cast<const float4*>(wp + (size_t)(k0 + 2) * 128);
    float4 w3 = *reinterpret_cast<const float4*>(wp + (size_t)(k0 + 3) * 128);
    acc[0][0] += a0.x * w0.x; acc[0][1] += a0.x * w0.y; acc[0][2] += a0.x * w0.z; acc[0][3] += a0.x * w0.w;
    acc[1][0] += a1.x * w0.x; acc[1][1] += a1.x * w0.y; acc[1][2] += a1.x * w0.z; acc[1][3] += a1.x * w0.w;
    acc[2][0] += a2.x * w0.x; acc[2][1] += a2.x * w0.y; acc[2][2] += a2.x * w0.z; acc[2][3] += a2.x * w0.w;
    acc[3][0] += a3.x * w0.x; acc[3][1] += a3.x * w0.y; acc[3][2] += a3.x * w0.z; acc[3][3] += a3.x * w0.w;
    acc[0][0] += a0.y * w1.x; acc[0][1] += a0.y * w1.y; acc[0][2] += a0.y * w1.z; acc[0][3] += a0.y * w1.w;
    acc[1][0] += a1.y * w1.x; acc[1][1] += a1.y * w1.y; acc[1][2] += a1.y * w1.z; acc[1][3] += a1.y * w1.w;
    acc[2][0] += a2.y * w1.x; acc[2][1] += a2.y * w1.y; acc[2][2] += a2.y * w1.z; acc[2][3] += a2.y * w1.w;
    acc[3][0] += a3.y * w1.x; acc[3][1] += a3.y * w1.y; acc[3][2] += a3.y * w1.z; acc[3][3] += a3.y * w1.w;
    acc[0][0] += a0.z * w2.x; acc[0][1] += a0.z * w2.y; acc[0][2] += a0.z * w2.z; acc[0][3] += a0.z * w2.w;
    acc[1][0] += a1.z * w2.x; acc[1][1] += a1.z * w2.y; acc[1][2] += a1.z * w2.z; acc[1][3] += a1.z * w2.w;
    acc[2][0] += a2.z * w2.x; acc[2][1] += a2.z * w2.y; acc[2][2] += a2.z * w2.z; acc[2][3] += a2.z * w2.w;
    acc[3][0] += a3.z * w2.x; acc[3][1] += a3.z * w2.y; acc[3][2] += a3.z * w2.z; acc[3][3] += a3.z * w2.w;
    acc[0][0] += a0.w * w3.x; acc[0][1] += a0.w * w3.y; acc[0][2] += a0.w * w3.z; acc[0][3] += a0.w * w3.w;
    acc[1][0] += a1.w * w3.x; acc[1][1] += a1.w * w3.y; acc[1][2] += a1.w * w3.z; acc[1][3] += a1.w * w3.w;
    acc[2][0] += a2.w * w3.x; acc[2][1] += a2.w * w3.y; acc[2][2] += a2.w * w3.z; acc[2][3] += a2.w * w3.w;
    acc[3][0] += a3.w * w3.x; acc[3][1] += a3.w * w3.y; acc[3][2] += a3.w * w3.z; acc[3][3] += a3.w * w3.w;
  }
  float4 bv = make_float4(0.f, 0.f, 0.f, 0.f);
  if (bias) bv = *reinterpret_cast<const float4*>(bias + col0 + c * 4);
  for (int i = 0; i < 4; ++i) {
    int row = r + i;
    if (row >= N) continue;
    float4 o;
    o.x = acc[i][0] + bv.x;
    o.y = acc[i][1] + bv.y;
    o.z = acc[i][2] + bv.z;
    o.w = acc[i][3] + bv.w;
    if (relu) {
      o.x = fmaxf(o.x, 0.f); o.y = fmaxf(o.y, 0.f);
      o.z = fmaxf(o.z, 0.f); o.w = fmaxf(o.w, 0.f);
    }
    *reinterpret_cast<float4*>(Y + (size_t)row * 128 + col0 + c * 4) = o;
  }
}

// ------------------------- GATv2: fused per-node pull (online softmax) ---
// 32 lanes per node; 8 nodes per 256-thread block. No atomics.
__global__ __launch_bounds__(256) void gat_node(
    const float* __restrict__ xl, const float* __restrict__ xr,
    const int* __restrict__ rowstart, const int* __restrict__ hist,
    const int* __restrict__ csr_src, const int* __restrict__ csr_eid,
    const float* __restrict__ ia, const float* __restrict__ mean_ea,
    const float* __restrict__ We, const float* __restrict__ att, const float* __restrict__ bias,
    float* __restrict__ out, int N, int relu) {
  __shared__ float sW0[128], sW1[128], sAtt[128], sBias[128];
  int t = threadIdx.x;
  if (t < 128) { sW0[t] = We[t]; sW1[t] = We[128 + t]; }
  else { int j = t - 128; sAtt[j] = att[j]; sBias[j] = bias[j]; }
  __syncthreads();
  int grp = t >> 5, lane = t & 31;
  int d = blockIdx.x * 8 + grp;
  if (d >= N) return;
  float4 w0 = *reinterpret_cast<const float4*>(sW0 + lane * 4);
  float4 w1 = *reinterpret_cast<const float4*>(sW1 + lane * 4);
  float4 at = *reinterpret_cast<const float4*>(sAtt + lane * 4);
  float4 xr4 = *reinterpret_cast<const float4*>(xr + (size_t)d * 128 + lane * 4);
  int st = rowstart[d], deg = hist[d];
  float m = -INFINITY, denom = 0.f;
  float4 acc = make_float4(0.f, 0.f, 0.f, 0.f);
  for (int i = -1; i < deg; ++i) {
    int s; float ea0, ea1;
    if (i < 0) {
      s = d; ea0 = mean_ea[2 * d]; ea1 = mean_ea[2 * d + 1];
    } else {
      int k = st + i;
      s = csr_src[k];
      int e = csr_eid[k];
      ea0 = ia[2 * e]; ea1 = ia[2 * e + 1];
    }
    float4 a = *reinterpret_cast<const float4*>(xl + (size_t)s * 128 + lane * 4);
    float4 v;
    v.x = a.x + xr4.x + ea0 * w0.x + ea1 * w1.x; v.x = v.x > 0.f ? v.x : 0.2f * v.x;
    v.y = a.y + xr4.y + ea0 * w0.y + ea1 * w1.y; v.y = v.y > 0.f ? v.y : 0.2f * v.y;
    v.z = a.z + xr4.z + ea0 * w0.z + ea1 * w1.z; v.z = v.z > 0.f ? v.z : 0.2f * v.z;
    v.w = a.w + xr4.w + ea0 * w0.w + ea1 * w1.w; v.w = v.w > 0.f ? v.w : 0.2f * v.w;
    float p = v.x * at.x + v.y * at.y + v.z * at.z + v.w * at.w;
#pragma unroll
    for (int off = 16; off; off >>= 1) p += __shfl_xor(p, off);
    if (p > m) {
      float sc = __expf(m - p);  // m = -inf -> 0 on first edge
      denom *= sc;
      acc.x *= sc; acc.y *= sc; acc.z *= sc; acc.w *= sc;
      m = p;
    }
    float w = __expf(p - m);
    denom += w;
    acc.x += w * a.x; acc.y += w * a.y; acc.z += w * a.z; acc.w += w * a.w;
  }
  float inv = 1.f / denom;
  float4 bv = *reinterpret_cast<const float4*>(sBias + lane * 4);
  float4 o;
  o.x = acc.x * inv + bv.x;
  o.y = acc.y * inv + bv.y;
  o.z = acc.z * inv + bv.z;
  o.w = acc.w * inv + bv.w;
  if (relu) {
    o.x = fmaxf(o.x, 0.f); o.y = fmaxf(o.y, 0.f);
    o.z = fmaxf(o.z, 0.f); o.w = fmaxf(o.w, 0.f);
  }
  *reinterpret_cast<float4*>(out + (size_t)d * 128 + lane * 4) = o;
}

// ------------------------- GCN: fused per-node pull ----------------------
__global__ __launch_bounds__(256) void zone_dinv_k(const int* __restrict__ rowstart, const int* __restrict__ hist,
                                                   const float* __restrict__ csr_w, float* __restrict__ dinv, int NZ) {
  int d = blockIdx.x * 256 + threadIdx.x;
  if (d >= NZ) return;
  int st = rowstart[d], deg = hist[d];
  float s = 1.f;  // self-loop weight
  for (int i = 0; i < deg; ++i) s += csr_w[st + i];
  dinv[d] = rsqrtf(s);
}

__global__ __launch_bounds__(256) void gcn_node(const float* __restrict__ h, const int* __restrict__ rowstart,
                                                const int* __restrict__ hist, const int* __restrict__ csr_src,
                                                const float* __restrict__ csr_w, const float* __restrict__ dinv,
                                                const float* __restrict__ bias, float* __restrict__ out,
                                                int NZ, int relu) {
  int t = threadIdx.x, grp = t >> 5, lane = t & 31;
  int d = blockIdx.x * 8 + grp;
  if (d >= NZ) return;
  float dv = dinv[d];
  float4 hd = *reinterpret_cast<const float4*>(h + (size_t)d * 128 + lane * 4);
  float4 acc;
  float dv2 = dv * dv;
  acc.x = dv2 * hd.x; acc.y = dv2 * hd.y; acc.z = dv2 * hd.z; acc.w = dv2 * hd.w;
  int st = rowstart[d], deg = hist[d];
  for (int i = 0; i < deg; ++i) {
    int s = csr_src[st + i];
    float coef = dinv[s] * csr_w[st + i] * dv;
    float4 a = *reinterpret_cast<const float4*>(h + (size_t)s * 128 + lane * 4);
    acc.x += coef * a.x; acc.y += coef * a.y; acc.z += coef * a.z; acc.w += coef * a.w;
  }
  float4 bv = *reinterpret_cast<const float4*>(bias + lane * 4);
  float4 o;
  o.x = acc.x + bv.x; o.y = acc.y + bv.y; o.z = acc.z + bv.z; o.w = acc.w + bv.w;
  if (relu) {
    o.x = fmaxf(o.x, 0.f); o.y = fmaxf(o.y, 0.f);
    o.z = fmaxf(o.z, 0.f); o.w = fmaxf(o.w, 0.f);
  }
  *reinterpret_cast<float4*>(out + (size_t)d * 128 + lane * 4) = o;
}

extern "C" void kernel_launch(void* const* d_in, const int* in_sizes, int n_in,
                              void* d_out, int out_size, void* d_ws, size_t ws_size,
                              hipStream_t stream) {
  const float* road_id_emb = (const float*)d_in[0];
  const float* len_W = (const float*)d_in[1];
  const float* len_b = (const float*)d_in[2];
  const float* type_emb = (const float*)d_in[3];
  const float* lon_W = (const float*)d_in[4];
  const float* lon_b = (const float*)d_in[5];
  const float* lat_W = (const float*)d_in[6];
  const float* lat_b = (const float*)d_in[7];
  const float* alen = (const float*)d_in[8];
  const int* atype = (const int*)d_in[9];
  const float* alon = (const float*)d_in[10];
  const float* alat = (const float*)d_in[11];
  const int* rei = (const int*)d_in[12];
  const float* ia = (const float*)d_in[13];
  const float* zone_emb = (const float*)d_in[28];
  const int* zei = (const int*)d_in[29];
  const float* zw = (const float*)d_in[30];
  const float* gcn1_W = (const float*)d_in[31];
  const float* gcn1_b = (const float*)d_in[32];
  const float* gcn2_W = (const float*)d_in[33];
  const float* gcn2_b = (const float*)d_in[34];

  const int N = in_sizes[8];          // 100000
  const int E = in_sizes[12] / 2;     // 400000
  const int NZ = in_sizes[28] / 128;  // 20000
  const int EZ = in_sizes[30];        // 160000

  const int* src = rei;
  const int* dst = rei + E;
  const int* zsrc = zei;
  const int* zdst = zei + EZ;

  float* ws = (float*)d_ws;
  float* A = ws;
  float* B = A + (size_t)N * 128;
  float* C = B + (size_t)N * 128;
  float* mean_ea = C + (size_t)N * 128;            // 2N
  int* rowstart = (int*)(mean_ea + 2 * (size_t)N); // N
  int* hist = rowstart + N;                        // N
  int* cursor = hist + N;                          // N
  int* csr_src = cursor + N;                       // E
  int* csr_eid = csr_src + E;                      // E
  int* bsum = csr_eid + E;                         // 256
  int* zrowstart = bsum + 256;                     // NZ
  int* zhist = zrowstart + NZ;                     // NZ
  int* zcursor = zhist + NZ;                       // NZ
  int* zcsr_src = zcursor + NZ;                    // EZ
  float* zcsr_w = (float*)(zcsr_src + EZ);         // EZ
  float* dinv = zcsr_w + EZ;                       // NZ

  float* road_out = (float*)d_out;
  float* zone_out = road_out + (size_t)N * 128;

  // ---- road node features ----
  feat_kernel<<<(N * 128 + 255) / 256, 256, 0, stream>>>(
      road_id_emb, len_W, len_b, type_emb, lon_W, lon_b, lat_W, lat_b,
      alen, atype, alon, alat, A, N);

  // ---- road CSR (dst-indexed) ----
  const int nbR = (N + 1023) / 1024;
  hipMemsetAsync(hist, 0, 2 * (size_t)N * sizeof(int), stream);  // hist + cursor
  hist_kernel<<<(E + 255) / 256, 256, 0, stream>>>(dst, hist, E);
  scan_local<<<nbR, 256, 0, stream>>>(hist, rowstart, bsum, N);
  scan_bsum<<<1, 256, 0, stream>>>(bsum, nbR);
  scan_add<<<(N + 255) / 256, 256, 0, stream>>>(rowstart, bsum, N);
  scatter_road<<<(E + 255) / 256, 256, 0, stream>>>(src, dst, rowstart, cursor, csr_src, csr_eid, E);
  mean_ea_kernel<<<(N + 255) / 256, 256, 0, stream>>>(rowstart, hist, csr_eid, ia, mean_ea, N);

  const int gemm_grid = ((N + 63) / 64) * 2;

  auto gat = [&](const float* xin, int base, float* xl, float* xr, float* outp, int relu) {
    const float* Wl = (const float*)d_in[base + 0];
    const float* bl = (const float*)d_in[base + 1];
    const float* Wr = (const float*)d_in[base + 2];
    const float* br = (const float*)d_in[base + 3];
    const float* We = (const float*)d_in[base + 4];
    const float* att = (const float*)d_in[base + 5];
    const float* bias = (const float*)d_in[base + 6];
    gemm128<<<gemm_grid, 256, 0, stream>>>(xin, Wl, bl, xl, N, 0);
    gemm128<<<gemm_grid, 256, 0, stream>>>(xin, Wr, br, xr, N, 0);
    gat_node<<<(N + 7) / 8, 256, 0, stream>>>(xl, xr, rowstart, hist, csr_src, csr_eid,
                                              ia, mean_ea, We, att, bias, outp, N, relu);
  };

  // layer 1: x=A, xl=C, xr=B, out=B (out aliases xr: each group reads xr[d] before writing out[d])
  gat(A, 14, C, B, B, 1);
  // layer 2: x=B, xl=C, xr=A, out=road_out
  gat(B, 21, C, A, road_out, 0);

  // ---- zone CSR + GCN (buffers alias A; road pipeline done by stream order) ----
  float* HG = A;
  float* ZA = A + (size_t)NZ * 128;

  const int nbZ = (NZ + 1023) / 1024;
  hipMemsetAsync(zhist, 0, 2 * (size_t)NZ * sizeof(int), stream);  // zhist + zcursor
  hist_kernel<<<(EZ + 255) / 256, 256, 0, stream>>>(zdst, zhist, EZ);
  scan_local<<<nbZ, 256, 0, stream>>>(zhist, zrowstart, bsum, NZ);
  scan_bsum<<<1, 256, 0, stream>>>(bsum, nbZ);
  scan_add<<<(NZ + 255) / 256, 256, 0, stream>>>(zrowstart, bsum, NZ);
  scatter_zone<<<(EZ + 255) / 256, 256, 0, stream>>>(zsrc, zdst, zw, zrowstart, zcursor, zcsr_src, zcsr_w, EZ);
  zone_dinv_k<<<(NZ + 255) / 256, 256, 0, stream>>>(zrowstart, zhist, zcsr_w, dinv, NZ);

  const int zgrid = ((NZ + 63) / 64) * 2;
  gemm128<<<zgrid, 256, 0, stream>>>(zone_emb, gcn1_W, nullptr, HG, NZ, 0);
  gcn_node<<<(NZ + 7) / 8, 256, 0, stream>>>(HG, zrowstart, zhist, zcsr_src, zcsr_w, dinv, gcn1_b, ZA, NZ, 1);
  gemm128<<<zgrid, 256, 0, stream>>>(ZA, gcn2_W, nullptr, HG, NZ, 0);
  gcn_node<<<(NZ + 7) / 8, 256, 0, stream>>>(HG, zrowstart, zhist, zcsr_src, zcsr_w, dinv, gcn2_b, zone_out, NZ, 0);
}

// Round 5
// 563.265 us; speedup vs baseline: 1.3771x; 1.3771x over previous
//
#include <hip/hip_runtime.h>
#include <math.h>

// ---------------------------------------------------------------------------
// RoadNetworkEncoder: 2x GATv2 (road) + 2x GCN (zone), f32, H=128.
// CSR pull-aggregation (no feature atomics), online softmax.
// Round 5: register-blocked dual GEMM. Round-4 cache-only GEMM was VMEM-issue
// bound (24% VALU): 8 global loads / 64 FMA. New: 8x4 register tile x2
// outputs -> 16 ds_read_b128 / 512 FMA, Wl+Wr fused (X staged once).
// ---------------------------------------------------------------------------

__global__ __launch_bounds__(256) void feat_kernel(
    const float* __restrict__ id_emb, const float* __restrict__ lenW, const float* __restrict__ lenb,
    const float* __restrict__ type_emb, const float* __restrict__ lonW, const float* __restrict__ lonb,
    const float* __restrict__ latW, const float* __restrict__ latb,
    const float* __restrict__ alen, const int* __restrict__ atype,
    const float* __restrict__ alon, const float* __restrict__ alat,
    float* __restrict__ x, int N) {
  int idx = blockIdx.x * 256 + threadIdx.x;
  if (idx >= N * 128) return;
  int node = idx >> 7, j = idx & 127;
  float v;
  if (j < 64) v = id_emb[(node << 6) + j];
  else if (j < 80) v = alen[node] * lenW[j - 64] + lenb[j - 64];
  else if (j < 96) v = type_emb[atype[node] * 16 + (j - 80)];
  else if (j < 112) v = alon[node] * lonW[j - 96] + lonb[j - 96];
  else v = alat[node] * latW[j - 112] + latb[j - 112];
  x[idx] = v;
}

// ------------------------- CSR build -------------------------

__global__ __launch_bounds__(256) void hist_kernel(const int* __restrict__ dst, int* __restrict__ hist, int E) {
  int e = blockIdx.x * 256 + threadIdx.x;
  if (e < E) atomicAdd(hist + dst[e], 1);
}

// exclusive scan, 1024 elems/block (256 thr x 4)
__global__ __launch_bounds__(256) void scan_local(const int* __restrict__ in, int* __restrict__ out,
                                                  int* __restrict__ bsum, int n) {
  __shared__ int lds[256];
  int t = threadIdx.x;
  int base = blockIdx.x * 1024 + t * 4;
  int v0 = base + 0 < n ? in[base + 0] : 0;
  int v1 = base + 1 < n ? in[base + 1] : 0;
  int v2 = base + 2 < n ? in[base + 2] : 0;
  int v3 = base + 3 < n ? in[base + 3] : 0;
  int s = v0 + v1 + v2 + v3;
  lds[t] = s;
  __syncthreads();
  for (int off = 1; off < 256; off <<= 1) {
    int x = (t >= off) ? lds[t - off] : 0;
    __syncthreads();
    if (t >= off) lds[t] += x;
    __syncthreads();
  }
  int excl = lds[t] - s;
  if (t == 255) bsum[blockIdx.x] = lds[255];
  if (base + 0 < n) out[base + 0] = excl;
  if (base + 1 < n) out[base + 1] = excl + v0;
  if (base + 2 < n) out[base + 2] = excl + v0 + v1;
  if (base + 3 < n) out[base + 3] = excl + v0 + v1 + v2;
}

__global__ __launch_bounds__(256) void scan_bsum(int* __restrict__ bsum, int nb) {
  __shared__ int lds[256];
  int t = threadIdx.x;
  int v = (t < nb) ? bsum[t] : 0;
  lds[t] = v;
  __syncthreads();
  for (int off = 1; off < 256; off <<= 1) {
    int x = (t >= off) ? lds[t - off] : 0;
    __syncthreads();
    if (t >= off) lds[t] += x;
    __syncthreads();
  }
  if (t < nb) bsum[t] = lds[t] - v;
}

__global__ __launch_bounds__(256) void scan_add(int* __restrict__ out, const int* __restrict__ bsum, int n) {
  int i = blockIdx.x * 256 + threadIdx.x;
  if (i < n) out[i] += bsum[i >> 10];
}

__global__ __launch_bounds__(256) void scatter_road(const int* __restrict__ src, const int* __restrict__ dst,
                                                    const int* __restrict__ rowstart, int* __restrict__ cursor,
                                                    int* __restrict__ csr_src, int* __restrict__ csr_eid, int E) {
  int e = blockIdx.x * 256 + threadIdx.x;
  if (e >= E) return;
  int d = dst[e];
  int idx = rowstart[d] + atomicAdd(cursor + d, 1);
  csr_src[idx] = src[e];
  csr_eid[idx] = e;
}

__global__ __launch_bounds__(256) void scatter_zone(const int* __restrict__ src, const int* __restrict__ dst,
                                                    const float* __restrict__ w,
                                                    const int* __restrict__ rowstart, int* __restrict__ cursor,
                                                    int* __restrict__ csr_src, float* __restrict__ csr_w, int E) {
  int e = blockIdx.x * 256 + threadIdx.x;
  if (e >= E) return;
  int d = dst[e];
  int idx = rowstart[d] + atomicAdd(cursor + d, 1);
  csr_src[idx] = src[e];
  csr_w[idx] = w[e];
}

__global__ __launch_bounds__(256) void mean_ea_kernel(const int* __restrict__ rowstart, const int* __restrict__ hist,
                                                      const int* __restrict__ csr_eid, const float* __restrict__ ia,
                                                      float* __restrict__ mea, int N) {
  int d = blockIdx.x * 256 + threadIdx.x;
  if (d >= N) return;
  int st = rowstart[d], deg = hist[d];
  float a = 0.f, b = 0.f;
  for (int i = 0; i < deg; ++i) {
    int e = csr_eid[st + i];
    a += ia[2 * e];
    b += ia[2 * e + 1];
  }
  float c = deg > 0 ? 1.f / (float)deg : 0.f;
  mea[2 * d] = a * c;
  mea[2 * d + 1] = b * c;
}

// ------------------------- register-blocked (dual) GEMM ------------------
// Yl = X@Wl (+bl), and if DUAL, Yr = X@Wr (+br). X:[N,128], W:[128,128].
// Block tile: 128 rows x 64 cols; thread tile: 8 rows x 4 cols (x2 outputs).
// Per 4-k window/thread: 8 X + 8(4) W ds_read_b128 feed 512(256) FMAs.
template <int DUAL>
__global__ __launch_bounds__(256) void gemm_rb(
    const float* __restrict__ X, const float* __restrict__ Wl, const float* __restrict__ Wr,
    const float* __restrict__ bl, const float* __restrict__ br,
    float* __restrict__ Yl, float* __restrict__ Yr, int N, int relu) {
  __shared__ float Xs[128][36];                    // stride 36: 16B-aligned rows, bank-offset 4 per row
  __shared__ float Wls[32 * 64];
  __shared__ float Wrs[DUAL ? 32 * 64 : 4];
  int t = threadIdx.x;
  int c4 = (t & 15) * 4;       // col within tile
  int g = t >> 4;              // row group: rows g + 16*i
  int row0 = (blockIdx.x >> 1) * 128;
  int col0 = (blockIdx.x & 1) * 64;

  float accl[8][4] = {{0.f}};
  float accr[8][4] = {{0.f}};

#pragma unroll 1
  for (int kb = 0; kb < 4; ++kb) {
    // stage X[128][32] (row-major, stride 36)
#pragma unroll
    for (int q = 0; q < 4; ++q) {
      int lin = q * 256 + t;                 // 0..1023
      int r = lin >> 3, kf = (lin & 7) * 4;
      int row = min(row0 + r, N - 1);
      *reinterpret_cast<float4*>(&Xs[r][kf]) =
          *reinterpret_cast<const float4*>(X + (size_t)row * 128 + kb * 32 + kf);
    }
    // stage W slabs [32][64]
#pragma unroll
    for (int q = 0; q < 2; ++q) {
      int lin = q * 256 + t;                 // 0..511
      int k = lin >> 4, cw = (lin & 15) * 4;
      *reinterpret_cast<float4*>(&Wls[k * 64 + cw]) =
          *reinterpret_cast<const float4*>(Wl + (size_t)(kb * 32 + k) * 128 + col0 + cw);
      if (DUAL)
        *reinterpret_cast<float4*>(&Wrs[k * 64 + cw]) =
            *reinterpret_cast<const float4*>(Wr + (size_t)(kb * 32 + k) * 128 + col0 + cw);
    }
    __syncthreads();
#pragma unroll 1
    for (int k4 = 0; k4 < 32; k4 += 4) {
      float4 l0 = *reinterpret_cast<const float4*>(&Wls[(k4 + 0) * 64 + c4]);
      float4 l1 = *reinterpret_cast<const float4*>(&Wls[(k4 + 1) * 64 + c4]);
      float4 l2 = *reinterpret_cast<const float4*>(&Wls[(k4 + 2) * 64 + c4]);
      float4 l3 = *reinterpret_cast<const float4*>(&Wls[(k4 + 3) * 64 + c4]);
      float4 r0, r1, r2, r3;
      if (DUAL) {
        r0 = *reinterpret_cast<const float4*>(&Wrs[(k4 + 0) * 64 + c4]);
        r1 = *reinterpret_cast<const float4*>(&Wrs[(k4 + 1) * 64 + c4]);
        r2 = *reinterpret_cast<const float4*>(&Wrs[(k4 + 2) * 64 + c4]);
        r3 = *reinterpret_cast<const float4*>(&Wrs[(k4 + 3) * 64 + c4]);
      }
#pragma unroll
      for (int i = 0; i < 8; ++i) {
        float4 xv = *reinterpret_cast<const float4*>(&Xs[g + 16 * i][k4]);
        accl[i][0] += xv.x * l0.x + xv.y * l1.x + xv.z * l2.x + xv.w * l3.x;
        accl[i][1] += xv.x * l0.y + xv.y * l1.y + xv.z * l2.y + xv.w * l3.y;
        accl[i][2] += xv.x * l0.z + xv.y * l1.z + xv.z * l2.z + xv.w * l3.z;
        accl[i][3] += xv.x * l0.w + xv.y * l1.w + xv.z * l2.w + xv.w * l3.w;
        if (DUAL) {
          accr[i][0] += xv.x * r0.x + xv.y * r1.x + xv.z * r2.x + xv.w * r3.x;
          accr[i][1] += xv.x * r0.y + xv.y * r1.y + xv.z * r2.y + xv.w * r3.y;
          accr[i][2] += xv.x * r0.z + xv.y * r1.z + xv.z * r2.z + xv.w * r3.z;
          accr[i][3] += xv.x * r0.w + xv.y * r1.w + xv.z * r2.w + xv.w * r3.w;
        }
      }
    }
    __syncthreads();
  }

  float4 blv = make_float4(0.f, 0.f, 0.f, 0.f);
  float4 brv = make_float4(0.f, 0.f, 0.f, 0.f);
  if (bl) blv = *reinterpret_cast<const float4*>(bl + col0 + c4);
  if (DUAL && br) brv = *reinterpret_cast<const float4*>(br + col0 + c4);
#pragma unroll
  for (int i = 0; i < 8; ++i) {
    int row = row0 + g + 16 * i;
    if (row >= N) continue;
    float4 o;
    o.x = accl[i][0] + blv.x; o.y = accl[i][1] + blv.y;
    o.z = accl[i][2] + blv.z; o.w = accl[i][3] + blv.w;
    if (relu) {
      o.x = fmaxf(o.x, 0.f); o.y = fmaxf(o.y, 0.f);
      o.z = fmaxf(o.z, 0.f); o.w = fmaxf(o.w, 0.f);
    }
    *reinterpret_cast<float4*>(Yl + (size_t)row * 128 + col0 + c4) = o;
    if (DUAL) {
      float4 p;
      p.x = accr[i][0] + brv.x; p.y = accr[i][1] + brv.y;
      p.z = accr[i][2] + brv.z; p.w = accr[i][3] + brv.w;
      *reinterpret_cast<float4*>(Yr + (size_t)row * 128 + col0 + c4) = p;
    }
  }
}

// ------------------------- GATv2: fused per-node pull (online softmax) ---
// 32 lanes per node; 8 nodes per 256-thread block. No atomics.
__global__ __launch_bounds__(256) void gat_node(
    const float* __restrict__ xl, const float* __restrict__ xr,
    const int* __restrict__ rowstart, const int* __restrict__ hist,
    const int* __restrict__ csr_src, const int* __restrict__ csr_eid,
    const float* __restrict__ ia, const float* __restrict__ mean_ea,
    const float* __restrict__ We, const float* __restrict__ att, const float* __restrict__ bias,
    float* __restrict__ out, int N, int relu) {
  __shared__ float sW0[128], sW1[128], sAtt[128], sBias[128];
  int t = threadIdx.x;
  if (t < 128) { sW0[t] = We[t]; sW1[t] = We[128 + t]; }
  else { int j = t - 128; sAtt[j] = att[j]; sBias[j] = bias[j]; }
  __syncthreads();
  int grp = t >> 5, lane = t & 31;
  int d = blockIdx.x * 8 + grp;
  if (d >= N) return;
  float4 w0 = *reinterpret_cast<const float4*>(sW0 + lane * 4);
  float4 w1 = *reinterpret_cast<const float4*>(sW1 + lane * 4);
  float4 at = *reinterpret_cast<const float4*>(sAtt + lane * 4);
  float4 xr4 = *reinterpret_cast<const float4*>(xr + (size_t)d * 128 + lane * 4);
  int st = rowstart[d], deg = hist[d];
  float m = -INFINITY, denom = 0.f;
  float4 acc = make_float4(0.f, 0.f, 0.f, 0.f);
  for (int i = -1; i < deg; ++i) {
    int s; float ea0, ea1;
    if (i < 0) {
      s = d; ea0 = mean_ea[2 * d]; ea1 = mean_ea[2 * d + 1];
    } else {
      int k = st + i;
      s = csr_src[k];
      int e = csr_eid[k];
      ea0 = ia[2 * e]; ea1 = ia[2 * e + 1];
    }
    float4 a = *reinterpret_cast<const float4*>(xl + (size_t)s * 128 + lane * 4);
    float4 v;
    v.x = a.x + xr4.x + ea0 * w0.x + ea1 * w1.x; v.x = v.x > 0.f ? v.x : 0.2f * v.x;
    v.y = a.y + xr4.y + ea0 * w0.y + ea1 * w1.y; v.y = v.y > 0.f ? v.y : 0.2f * v.y;
    v.z = a.z + xr4.z + ea0 * w0.z + ea1 * w1.z; v.z = v.z > 0.f ? v.z : 0.2f * v.z;
    v.w = a.w + xr4.w + ea0 * w0.w + ea1 * w1.w; v.w = v.w > 0.f ? v.w : 0.2f * v.w;
    float p = v.x * at.x + v.y * at.y + v.z * at.z + v.w * at.w;
#pragma unroll
    for (int off = 16; off; off >>= 1) p += __shfl_xor(p, off);
    if (p > m) {
      float sc = __expf(m - p);  // m = -inf -> 0 on first edge
      denom *= sc;
      acc.x *= sc; acc.y *= sc; acc.z *= sc; acc.w *= sc;
      m = p;
    }
    float w = __expf(p - m);
    denom += w;
    acc.x += w * a.x; acc.y += w * a.y; acc.z += w * a.z; acc.w += w * a.w;
  }
  float inv = 1.f / denom;
  float4 bv = *reinterpret_cast<const float4*>(sBias + lane * 4);
  float4 o;
  o.x = acc.x * inv + bv.x;
  o.y = acc.y * inv + bv.y;
  o.z = acc.z * inv + bv.z;
  o.w = acc.w * inv + bv.w;
  if (relu) {
    o.x = fmaxf(o.x, 0.f); o.y = fmaxf(o.y, 0.f);
    o.z = fmaxf(o.z, 0.f); o.w = fmaxf(o.w, 0.f);
  }
  *reinterpret_cast<float4*>(out + (size_t)d * 128 + lane * 4) = o;
}

// ------------------------- GCN: fused per-node pull ----------------------
__global__ __launch_bounds__(256) void zone_dinv_k(const int* __restrict__ rowstart, const int* __restrict__ hist,
                                                   const float* __restrict__ csr_w, float* __restrict__ dinv, int NZ) {
  int d = blockIdx.x * 256 + threadIdx.x;
  if (d >= NZ) return;
  int st = rowstart[d], deg = hist[d];
  float s = 1.f;  // self-loop weight
  for (int i = 0; i < deg; ++i) s += csr_w[st + i];
  dinv[d] = rsqrtf(s);
}

__global__ __launch_bounds__(256) void gcn_node(const float* __restrict__ h, const int* __restrict__ rowstart,
                                                const int* __restrict__ hist, const int* __restrict__ csr_src,
                                                const float* __restrict__ csr_w, const float* __restrict__ dinv,
                                                const float* __restrict__ bias, float* __restrict__ out,
                                                int NZ, int relu) {
  int t = threadIdx.x, grp = t >> 5, lane = t & 31;
  int d = blockIdx.x * 8 + grp;
  if (d >= NZ) return;
  float dv = dinv[d];
  float4 hd = *reinterpret_cast<const float4*>(h + (size_t)d * 128 + lane * 4);
  float4 acc;
  float dv2 = dv * dv;
  acc.x = dv2 * hd.x; acc.y = dv2 * hd.y; acc.z = dv2 * hd.z; acc.w = dv2 * hd.w;
  int st = rowstart[d], deg = hist[d];
  for (int i = 0; i < deg; ++i) {
    int s = csr_src[st + i];
    float coef = dinv[s] * csr_w[st + i] * dv;
    float4 a = *reinterpret_cast<const float4*>(h + (size_t)s * 128 + lane * 4);
    acc.x += coef * a.x; acc.y += coef * a.y; acc.z += coef * a.z; acc.w += coef * a.w;
  }
  float4 bv = *reinterpret_cast<const float4*>(bias + lane * 4);
  float4 o;
  o.x = acc.x + bv.x; o.y = acc.y + bv.y; o.z = acc.z + bv.z; o.w = acc.w + bv.w;
  if (relu) {
    o.x = fmaxf(o.x, 0.f); o.y = fmaxf(o.y, 0.f);
    o.z = fmaxf(o.z, 0.f); o.w = fmaxf(o.w, 0.f);
  }
  *reinterpret_cast<float4*>(out + (size_t)d * 128 + lane * 4) = o;
}

extern "C" void kernel_launch(void* const* d_in, const int* in_sizes, int n_in,
                              void* d_out, int out_size, void* d_ws, size_t ws_size,
                              hipStream_t stream) {
  const float* road_id_emb = (const float*)d_in[0];
  const float* len_W = (const float*)d_in[1];
  const float* len_b = (const float*)d_in[2];
  const float* type_emb = (const float*)d_in[3];
  const float* lon_W = (const float*)d_in[4];
  const float* lon_b = (const float*)d_in[5];
  const float* lat_W = (const float*)d_in[6];
  const float* lat_b = (const float*)d_in[7];
  const float* alen = (const float*)d_in[8];
  const int* atype = (const int*)d_in[9];
  const float* alon = (const float*)d_in[10];
  const float* alat = (const float*)d_in[11];
  const int* rei = (const int*)d_in[12];
  const float* ia = (const float*)d_in[13];
  const float* zone_emb = (const float*)d_in[28];
  const int* zei = (const int*)d_in[29];
  const float* zw = (const float*)d_in[30];
  const float* gcn1_W = (const float*)d_in[31];
  const float* gcn1_b = (const float*)d_in[32];
  const float* gcn2_W = (const float*)d_in[33];
  const float* gcn2_b = (const float*)d_in[34];

  const int N = in_sizes[8];          // 100000
  const int E = in_sizes[12] / 2;     // 400000
  const int NZ = in_sizes[28] / 128;  // 20000
  const int EZ = in_sizes[30];        // 160000

  const int* src = rei;
  const int* dst = rei + E;
  const int* zsrc = zei;
  const int* zdst = zei + EZ;

  float* ws = (float*)d_ws;
  float* A = ws;
  float* B = A + (size_t)N * 128;
  float* C = B + (size_t)N * 128;
  float* mean_ea = C + (size_t)N * 128;            // 2N
  int* rowstart = (int*)(mean_ea + 2 * (size_t)N); // N
  int* hist = rowstart + N;                        // N
  int* cursor = hist + N;                          // N
  int* csr_src = cursor + N;                       // E
  int* csr_eid = csr_src + E;                      // E
  int* bsum = csr_eid + E;                         // 256
  int* zrowstart = bsum + 256;                     // NZ
  int* zhist = zrowstart + NZ;                     // NZ
  int* zcursor = zhist + NZ;                       // NZ
  int* zcsr_src = zcursor + NZ;                    // EZ
  float* zcsr_w = (float*)(zcsr_src + EZ);         // EZ
  float* dinv = zcsr_w + EZ;                       // NZ

  float* road_out = (float*)d_out;
  float* zone_out = road_out + (size_t)N * 128;

  // ---- road node features ----
  feat_kernel<<<(N * 128 + 255) / 256, 256, 0, stream>>>(
      road_id_emb, len_W, len_b, type_emb, lon_W, lon_b, lat_W, lat_b,
      alen, atype, alon, alat, A, N);

  // ---- road CSR (dst-indexed) ----
  const int nbR = (N + 1023) / 1024;
  hipMemsetAsync(hist, 0, 2 * (size_t)N * sizeof(int), stream);  // hist + cursor
  hist_kernel<<<(E + 255) / 256, 256, 0, stream>>>(dst, hist, E);
  scan_local<<<nbR, 256, 0, stream>>>(hist, rowstart, bsum, N);
  scan_bsum<<<1, 256, 0, stream>>>(bsum, nbR);
  scan_add<<<(N + 255) / 256, 256, 0, stream>>>(rowstart, bsum, N);
  scatter_road<<<(E + 255) / 256, 256, 0, stream>>>(src, dst, rowstart, cursor, csr_src, csr_eid, E);
  mean_ea_kernel<<<(N + 255) / 256, 256, 0, stream>>>(rowstart, hist, csr_eid, ia, mean_ea, N);

  const int gemm_grid = ((N + 127) / 128) * 2;

  auto gat = [&](const float* xin, int base, float* xl, float* xr, float* outp, int relu) {
    const float* Wl = (const float*)d_in[base + 0];
    const float* bl = (const float*)d_in[base + 1];
    const float* Wr = (const float*)d_in[base + 2];
    const float* br = (const float*)d_in[base + 3];
    const float* We = (const float*)d_in[base + 4];
    const float* att = (const float*)d_in[base + 5];
    const float* bias = (const float*)d_in[base + 6];
    gemm_rb<1><<<gemm_grid, 256, 0, stream>>>(xin, Wl, Wr, bl, br, xl, xr, N, 0);
    gat_node<<<(N + 7) / 8, 256, 0, stream>>>(xl, xr, rowstart, hist, csr_src, csr_eid,
                                              ia, mean_ea, We, att, bias, outp, N, relu);
  };

  // layer 1: x=A, xl=C, xr=B, out=B (out aliases xr: group reads xr[d] before writing out[d])
  gat(A, 14, C, B, B, 1);
  // layer 2: x=B, xl=C, xr=A, out=road_out
  gat(B, 21, C, A, road_out, 0);

  // ---- zone CSR + GCN (buffers alias A; road pipeline done by stream order) ----
  float* HG = A;
  float* ZA = A + (size_t)NZ * 128;

  const int nbZ = (NZ + 1023) / 1024;
  hipMemsetAsync(zhist, 0, 2 * (size_t)NZ * sizeof(int), stream);  // zhist + zcursor
  hist_kernel<<<(EZ + 255) / 256, 256, 0, stream>>>(zdst, zhist, EZ);
  scan_local<<<nbZ, 256, 0, stream>>>(zhist, zrowstart, bsum, NZ);
  scan_bsum<<<1, 256, 0, stream>>>(bsum, nbZ);
  scan_add<<<(NZ + 255) / 256, 256, 0, stream>>>(zrowstart, bsum, NZ);
  scatter_zone<<<(EZ + 255) / 256, 256, 0, stream>>>(zsrc, zdst, zw, zrowstart, zcursor, zcsr_src, zcsr_w, EZ);
  zone_dinv_k<<<(NZ + 255) / 256, 256, 0, stream>>>(zrowstart, zhist, zcsr_w, dinv, NZ);

  const int zgrid = ((NZ + 127) / 128) * 2;
  gemm_rb<0><<<zgrid, 256, 0, stream>>>(zone_emb, gcn1_W, nullptr, nullptr, nullptr, HG, nullptr, NZ, 0);
  gcn_node<<<(NZ + 7) / 8, 256, 0, stream>>>(HG, zrowstart, zhist, zcsr_src, zcsr_w, dinv, gcn1_b, ZA, NZ, 1);
  gemm_rb<0><<<zgrid, 256, 0, stream>>>(ZA, gcn2_W, nullptr, nullptr, nullptr, HG, nullptr, NZ, 0);
  gcn_node<<<(NZ + 7) / 8, 256, 0, stream>>>(HG, zrowstart, zhist, zcsr_src, zcsr_w, dinv, gcn2_b, zone_out, NZ, 0);
}